// Round 13
// baseline (164.339 us; speedup 1.0000x reference)
//
#include <hip/hip_runtime.h>
#include <stdint.h>

// SimCLR loss, B=4096, D=512, TAU=0.1.  out[0]=loss, out[1]=acc(%).
//
// Round 13: round-12 (Gram symmetry, MX fp8, dual harvest) with the finalize
// zeroing RACE removed (block 0 zeroed out[] while others atomicAdd'ed —
// the round-12 correctness failure). zero_out_kernel owns the zeroing.
//   block = (pair bi<=bj, v): v=0 stages a_j cols, v=1 stages b_j cols.
//   accA = a_i . cols -> row-dir full_a rows i (aa / ab part)
//   accB = b_i . cols -> row-dir full_b rows i (ba / bb part)
//   col-dir (skip when bi==bj: row-dir already covers the symmetric tile):
//     v=0: col c gets accA col (aa^T) + accB col (ab_{c,i}) -> full_a row c
//     v=1: col c gets accA col (ba_{c,i}) + accB col (bb^T) -> full_b row c
// Diag blocks mask (i,i): aa/bb masked diag AND ab/ba label (label re-added
// exactly from fp32 diag[] in finalize). Fixed-max softmax (logits bounded
// by 10) -> additive partials -> atomicAdd; full_a row max via atomicMax on
// bias-encoded bits. fp8 dataset = 4MB -> resident in every XCD L2.

#define BN 4096
#define DK 512            // K elements = bytes per row in fp8
#define NB 32             // 128-row panels
#define NEG_BIG -1e30f
#define SCL 0.15625f      // 1/(8*8*TAU)
#define SCL2 0.225396744f // SCL * log2(e)
#define C2 14.4269504f    // 10 * log2(e)
#define TILE_BYTES (32 * DK)  // 16 KB per 32-col fp8 tile

typedef __attribute__((ext_vector_type(16))) float floatx16;
typedef __attribute__((ext_vector_type(8))) int intx8;

// ---------------- prep: normalize, fp8-pack (K-permuted), label, zero -----
// Permuted layout: byte position kc2*32 + h*16 + t*8 + j holds original
// k = kc2*32 + t*16 + h*8 + j.  16B chunk (kc2,h) = K=16-sub-block operand
// bytes; chunks (2i,h),(2i+1,h) concatenated = one K=64 MX operand half.
__global__ void __launch_bounds__(256) prep_kernel(
    const float* __restrict__ A, const float* __restrict__ Bv,
    unsigned char* __restrict__ An, unsigned char* __restrict__ Bn,
    float* __restrict__ diag, float* __restrict__ zero_region) {
  {  // zero accLA/accLB/accMA (harness poisons ws with 0xAA)
    const int idx = blockIdx.x * 256 + threadIdx.x;
    if (idx < 3 * BN) zero_region[idx] = 0.0f;
  }
  const int w = threadIdx.x >> 6, lane = threadIdx.x & 63;
  const int row = blockIdx.x * 4 + w;
  const float4* pa4 = (const float4*)(A + (size_t)row * DK);
  const float4* pb4 = (const float4*)(Bv + (size_t)row * DK);
  float4 a0 = pa4[lane * 2], a1 = pa4[lane * 2 + 1];  // k = lane*8 .. +7
  float4 b0 = pb4[lane * 2], b1 = pb4[lane * 2 + 1];
  float ssa = a0.x * a0.x + a0.y * a0.y + a0.z * a0.z + a0.w * a0.w +
              a1.x * a1.x + a1.y * a1.y + a1.z * a1.z + a1.w * a1.w;
  float ssb = b0.x * b0.x + b0.y * b0.y + b0.z * b0.z + b0.w * b0.w +
              b1.x * b1.x + b1.y * b1.y + b1.z * b1.z + b1.w * b1.w;
  float sab = a0.x * b0.x + a0.y * b0.y + a0.z * b0.z + a0.w * b0.w +
              a1.x * b1.x + a1.y * b1.y + a1.z * b1.z + a1.w * b1.w;
#pragma unroll
  for (int off = 32; off > 0; off >>= 1) {
    ssa += __shfl_xor(ssa, off);
    ssb += __shfl_xor(ssb, off);
    sab += __shfl_xor(sab, off);
  }
  float na = fmaxf(sqrtf(ssa), 1e-12f);
  float nb = fmaxf(sqrtf(ssb), 1e-12f);
  const float s = 8.0f;  // fp8 pre-scale: keeps elems mid-range in e4m3
  float sa = s / na, sb = s / nb;
  const int doff = (lane >> 2) * 32 + (lane & 1) * 16 + ((lane >> 1) & 1) * 8;
  {
    int v0 = __builtin_amdgcn_cvt_pk_fp8_f32(a0.x * sa, a0.y * sa, 0, false);
    v0 = __builtin_amdgcn_cvt_pk_fp8_f32(a0.z * sa, a0.w * sa, v0, true);
    int v1 = __builtin_amdgcn_cvt_pk_fp8_f32(a1.x * sa, a1.y * sa, 0, false);
    v1 = __builtin_amdgcn_cvt_pk_fp8_f32(a1.z * sa, a1.w * sa, v1, true);
    int2 pv; pv.x = v0; pv.y = v1;
    *(int2*)(An + (size_t)row * DK + doff) = pv;
  }
  {
    int v0 = __builtin_amdgcn_cvt_pk_fp8_f32(b0.x * sb, b0.y * sb, 0, false);
    v0 = __builtin_amdgcn_cvt_pk_fp8_f32(b0.z * sb, b0.w * sb, v0, true);
    int v1 = __builtin_amdgcn_cvt_pk_fp8_f32(b1.x * sb, b1.y * sb, 0, false);
    v1 = __builtin_amdgcn_cvt_pk_fp8_f32(b1.z * sb, b1.w * sb, v1, true);
    int2 pv; pv.x = v0; pv.y = v1;
    *(int2*)(Bn + (size_t)row * DK + doff) = pv;
  }
  if (lane == 0) diag[row] = (sab / (na * nb)) * 10.0f;  // exact fp32 /TAU
}

// ---------------- tiles: symmetric pair blocks, MX fp8, dual harvest ------
// grid = 528 pairs x 2 views = 1056 blocks (~4/CU). 4 waves/block, wave owns
// 32 rows of panel bi (both views resident); 4 iters of 32-col tiles from
// panel bj (view v). 16 KB tiles, dbuf LDS (32 KB/block).
__global__ void __launch_bounds__(256, 2) tiles_kernel(
    const unsigned char* __restrict__ An, const unsigned char* __restrict__ Bn,
    float* __restrict__ accLA, float* __restrict__ accLB,
    unsigned* __restrict__ accMA) {
  __shared__ __align__(16) unsigned char smem[2 * TILE_BYTES];  // 32 KB

  // decode (bi, bj, v)
  int p = blockIdx.x >> 1;
  const int v = blockIdx.x & 1;
  int bi = 0;
  while (p >= NB - bi) { p -= NB - bi; ++bi; }
  const int bj = bi + p;
  const bool diagb = (bi == bj);

  const int tid = threadIdx.x;
  const int lane = tid & 63, w = tid >> 6;
  const int n5 = lane & 31, h = lane >> 5;
  const int r0 = bi * 128;
  const int myrow = r0 + w * 32 + n5;
  const int c0 = bj * 128;  // column panel base

  // both views' left K=64 MX operands: aw[i] = chunks (2i,h)||(2i+1,h)
  intx8 awA[8], awB[8];
  {
    const unsigned char* pA = An + (size_t)myrow * DK + h * 16;
    const unsigned char* pB = Bn + (size_t)myrow * DK + h * 16;
#pragma unroll
    for (int i = 0; i < 8; ++i) {
      int4 q0 = *(const int4*)(pA + i * 64);
      int4 q1 = *(const int4*)(pA + i * 64 + 32);
      intx8 va = {q0.x, q0.y, q0.z, q0.w, q1.x, q1.y, q1.z, q1.w};
      awA[i] = va;
      q0 = *(const int4*)(pB + i * 64);
      q1 = *(const int4*)(pB + i * 64 + 32);
      intx8 vb = {q0.x, q0.y, q0.z, q0.w, q1.x, q1.y, q1.z, q1.w};
      awB[i] = vb;
    }
  }

  // row-dir state (rows of panel bi): lA -> full_a, lB -> full_b; mx = full_a
  float lA[16], lB[16], mx[16];
#pragma unroll
  for (int r = 0; r < 16; ++r) { lA[r] = 0.f; lB[r] = 0.f; mx[r] = NEG_BIG; }

  const unsigned char* csrc = (v == 0) ? An : Bn;  // column view
  // stage a 32-col fp8 tile (16 KB); one inst = 2 cols (h=0 even, h=1 odd).
  // XOR swizzle: physical 16B chunk pp of col c holds logical chunk pp^(c&7).
  auto stage = [&](unsigned char* buf, int t) {
    const int cb = c0 + t * 32;
#pragma unroll
    for (int ii = 0; ii < 4; ++ii) {  // wave w: colpairs w*4 .. w*4+3
      const int cp = w * 4 + ii;
      const int cl = cp * 2 + h;
      const unsigned char* src =
          csrc + (size_t)(cb + cl) * DK + ((n5 ^ (cl & 7)) * 16);
      __builtin_amdgcn_global_load_lds(
          (const __attribute__((address_space(1))) void*)src,
          (__attribute__((address_space(3))) void*)(buf + cp * 1024),
          16, 0, 0);
    }
  };

  stage(smem, 0);
  __syncthreads();

  const int swz = n5 & 7;
  for (int t = 0; t < 4; ++t) {
    unsigned char* cur = smem + (t & 1) * TILE_BYTES;
    unsigned char* nxt = smem + ((t + 1) & 1) * TILE_BYTES;
    if (t < 3) stage(nxt, t + 1);  // prefetch; drained at this iter's barrier

    floatx16 accA, accB;
#pragma unroll
    for (int r = 0; r < 16; ++r) { accA[r] = 0.f; accB[r] = 0.f; }

    // B K=64 operand: logical chunks (4i+h),(4i+2+h) of col n5; one staged
    // operand feeds BOTH left views (a_i and b_i).
    const unsigned char* bbase = cur + (size_t)n5 * DK;
#pragma unroll
    for (int i = 0; i < 8; ++i) {
      const int p1 = ((4 * i + h) ^ swz) * 16;
      const int p2 = ((4 * i + 2 + h) ^ swz) * 16;
      int4 q0 = *(const int4*)(bbase + p1);
      int4 q1 = *(const int4*)(bbase + p2);
      intx8 bw = {q0.x, q0.y, q0.z, q0.w, q1.x, q1.y, q1.z, q1.w};
      accA = __builtin_amdgcn_mfma_scale_f32_32x32x64_f8f6f4(
          awA[i], bw, accA, 0, 0, 0, 0x7F7F7F7F, 0, 0x7F7F7F7F);
      accB = __builtin_amdgcn_mfma_scale_f32_32x32x64_f8f6f4(
          awB[i], bw, accB, 0, 0, 0, 0x7F7F7F7F, 0, 0x7F7F7F7F);
    }

    // harvest: row-dir always; col-dir only off-diagonal.
    const int colbase = c0 + t * 32;
    float cS = 0.f, cM = NEG_BIG;  // col partials (this lane's col = colbase+n5)
#pragma unroll
    for (int r = 0; r < 16; ++r) {
      float vA = accA[r], vB = accB[r];
      if (diagb) {  // mask (i,i): aa/bb diag and ab/ba label (re-added later)
        const int rowg = r0 + w * 32 + (r & 3) + 8 * (r >> 2) + 4 * h;
        if (rowg == colbase + n5) { vA = NEG_BIG; vB = NEG_BIG; }
      }
      mx[r] = fmaxf(mx[r], vA);  // accA is always a full_a contribution
      float eA = exp2f(fmaf(vA, SCL2, -C2));
      float eB = exp2f(fmaf(vB, SCL2, -C2));
      lA[r] += eA;
      lB[r] += eB;
      cS += eA + eB;  // both accs' col c target the same problem (see header)
      if (v == 0) cM = fmaxf(cM, fmaxf(vA, vB));  // full_a col max
    }
    if (!diagb) {
      cS += __shfl_xor(cS, 32);  // merge the two half-wave row-groups
      if (v == 0) cM = fmaxf(cM, __shfl_xor(cM, 32));
      if (h == 0) {
        float* dst = v ? accLB : accLA;
        atomicAdd(&dst[colbase + n5], cS);
        if (v == 0)
          atomicMax(&accMA[colbase + n5],
                    __float_as_uint(cM * SCL + 20.0f));
      }
    }
    __syncthreads();  // cur consumed by all; nxt's DMA drained
  }

  // row-dir flush: merge across the 32 n5-lanes (cols), then atomics
#pragma unroll
  for (int off = 1; off < 32; off <<= 1)
#pragma unroll
    for (int r = 0; r < 16; ++r) {
      lA[r] += __shfl_xor(lA[r], off);
      lB[r] += __shfl_xor(lB[r], off);
      mx[r] = fmaxf(mx[r], __shfl_xor(mx[r], off));
    }
  if (n5 == 0) {
#pragma unroll
    for (int r = 0; r < 16; ++r) {
      const int row = r0 + w * 32 + (r & 3) + 8 * (r >> 2) + 4 * h;
      atomicAdd(&accLA[row], lA[r]);
      atomicAdd(&accLB[row], lB[r]);
      atomicMax(&accMA[row], __float_as_uint(mx[r] * SCL + 20.0f));
    }
  }
}

// ---------------- finalize: add label, loss + accuracy reduce -------------
// NOTE: no zeroing here — zero_out_kernel runs before the pipeline. A zero
// in this kernel would race with other blocks' atomicAdd (round-12 bug).
__global__ void __launch_bounds__(256) finalize_kernel(
    const float* __restrict__ accLA, const float* __restrict__ accLB,
    const unsigned* __restrict__ accMA, const float* __restrict__ diag,
    float* __restrict__ out) {
  const int row = blockIdx.x * 256 + threadIdx.x;
  const float SA = accLA[row], SB = accLB[row];
  const float MA = __uint_as_float(accMA[row]) - 20.0f;  // max non-label logit
  const float d = diag[row];
  const float eL = exp2f(fmaf(d, 1.44269504f, -C2));     // exp(d-10)
  float lossi = (10.0f + logf(SA + eL) - d) + (10.0f + logf(SB + eL) - d);
  float corr = (d >= MA) ? 1.f : 0.f;  // argmax(full_a)==label
#pragma unroll
  for (int off = 32; off > 0; off >>= 1) {
    lossi += __shfl_xor(lossi, off);
    corr += __shfl_xor(corr, off);
  }
  __shared__ float sred[2][4];
  if ((threadIdx.x & 63) == 0) {
    int w = threadIdx.x >> 6;
    sred[0][w] = lossi; sred[1][w] = corr;
  }
  __syncthreads();
  if (threadIdx.x == 0) {
    float ls = sred[0][0] + sred[0][1] + sred[0][2] + sred[0][3];
    float cs = sred[1][0] + sred[1][1] + sred[1][2] + sred[1][3];
    atomicAdd(&out[0], ls * (1.0f / 8192.0f));    // mean over rows, /2
    atomicAdd(&out[1], cs * (100.0f / 4096.0f));  // accuracy %
  }
}

// zero the two outputs before finalize accumulates (out poisoned by harness)
__global__ void zero_out_kernel(float* out) {
  if (threadIdx.x < 2) out[threadIdx.x] = 0.0f;
}

extern "C" void kernel_launch(void* const* d_in, const int* in_sizes, int n_in,
                              void* d_out, int out_size, void* d_ws, size_t ws_size,
                              hipStream_t stream) {
  const float* A = (const float*)d_in[0];
  const float* Bv = (const float*)d_in[1];
  unsigned char* An = (unsigned char*)d_ws;                   // 4096x512 fp8
  unsigned char* Bn = An + (size_t)BN * DK;                   // 4096x512 fp8
  float* diag = (float*)(Bn + (size_t)BN * DK);               // 4096 f32
  float* accLA = diag + BN;                                   // 4096 f32
  float* accLB = accLA + BN;                                  // 4096 f32
  unsigned* accMA = (unsigned*)(accLB + BN);                  // 4096 u32
  float* out = (float*)d_out;

  zero_out_kernel<<<1, 64, 0, stream>>>(out);
  prep_kernel<<<BN / 4, 256, 0, stream>>>(A, Bv, An, Bn, diag, accLA);
  tiles_kernel<<<NB * (NB + 1), 256, 0, stream>>>(An, Bn, accLA, accLB, accMA);
  finalize_kernel<<<BN / 256, 256, 0, stream>>>(accLA, accLB, accMA, diag, out);
}

// Round 14
// 146.051 us; speedup vs baseline: 1.1252x; 1.1252x over previous
//
#include <hip/hip_runtime.h>
#include <stdint.h>

// SimCLR loss, B=4096, D=512, TAU=0.1.  out[0]=loss, out[1]=acc(%).
//
// Round 14: symmetric schedule (verified correct in r13) with the two
// measured overheads fixed:
//  (a) v merged into the block: one block per pair (bi<=bj), 528 blocks,
//      8 K-iters per prologue (r13: 1056 blocks x 4 iters).
//  (b) col-direction partials go to LDS (plain stores) and ALL global
//      atomics happen once at block end — r13 drained contended atomics at
//      every per-iter barrier (vmcnt(0) includes atomic RMWs).
// Mapping (unchanged from r13):
//   accA = a_i . cols, accB = b_i . cols   (cols = view v of panel bj)
//   row-dir: accA -> full_a rows i, accB -> full_b rows i (both v)
//   col-dir (bi<bj only): v=0 -> full_a row c gets accA col + accB col;
//                         v=1 -> full_b row c gets accB col + accA col.
// Diag blocks mask (i,i) (aa/bb masked diag AND ab/ba label; label re-added
// exactly from fp32 diag[] in finalize). Fixed-max softmax (logits bounded
// by 10) -> additive partials; full_a max via atomicMax on biased bits.

#define BN 4096
#define DK 512            // K elements = bytes per row in fp8
#define NB 32             // 128-row panels
#define NEG_BIG -1e30f
#define SCL 0.15625f      // 1/(8*8*TAU)
#define SCL2 0.225396744f // SCL * log2(e)
#define C2 14.4269504f    // 10 * log2(e)
#define TILE_BYTES (32 * DK)  // 16 KB per 32-col fp8 tile

typedef __attribute__((ext_vector_type(16))) float floatx16;
typedef __attribute__((ext_vector_type(8))) int intx8;

// ---------------- prep: normalize, fp8-pack (K-permuted), label, zero -----
// Permuted layout: byte position kc2*32 + h*16 + t*8 + j holds original
// k = kc2*32 + t*16 + h*8 + j.  16B chunk (kc2,h) = K=16-sub-block operand
// bytes; chunks (2i,h),(2i+1,h) concatenated = one K=64 MX operand half.
__global__ void __launch_bounds__(256) prep_kernel(
    const float* __restrict__ A, const float* __restrict__ Bv,
    unsigned char* __restrict__ An, unsigned char* __restrict__ Bn,
    float* __restrict__ diag, float* __restrict__ zero_region) {
  {  // zero accLA/accLB/accMA (harness poisons ws with 0xAA)
    const int idx = blockIdx.x * 256 + threadIdx.x;
    if (idx < 3 * BN) zero_region[idx] = 0.0f;
  }
  const int w = threadIdx.x >> 6, lane = threadIdx.x & 63;
  const int row = blockIdx.x * 4 + w;
  const float4* pa4 = (const float4*)(A + (size_t)row * DK);
  const float4* pb4 = (const float4*)(Bv + (size_t)row * DK);
  float4 a0 = pa4[lane * 2], a1 = pa4[lane * 2 + 1];  // k = lane*8 .. +7
  float4 b0 = pb4[lane * 2], b1 = pb4[lane * 2 + 1];
  float ssa = a0.x * a0.x + a0.y * a0.y + a0.z * a0.z + a0.w * a0.w +
              a1.x * a1.x + a1.y * a1.y + a1.z * a1.z + a1.w * a1.w;
  float ssb = b0.x * b0.x + b0.y * b0.y + b0.z * b0.z + b0.w * b0.w +
              b1.x * b1.x + b1.y * b1.y + b1.z * b1.z + b1.w * b1.w;
  float sab = a0.x * b0.x + a0.y * b0.y + a0.z * b0.z + a0.w * b0.w +
              a1.x * b1.x + a1.y * b1.y + a1.z * b1.z + a1.w * b1.w;
#pragma unroll
  for (int off = 32; off > 0; off >>= 1) {
    ssa += __shfl_xor(ssa, off);
    ssb += __shfl_xor(ssb, off);
    sab += __shfl_xor(sab, off);
  }
  float na = fmaxf(sqrtf(ssa), 1e-12f);
  float nb = fmaxf(sqrtf(ssb), 1e-12f);
  const float s = 8.0f;  // fp8 pre-scale: keeps elems mid-range in e4m3
  float sa = s / na, sb = s / nb;
  const int doff = (lane >> 2) * 32 + (lane & 1) * 16 + ((lane >> 1) & 1) * 8;
  {
    int v0 = __builtin_amdgcn_cvt_pk_fp8_f32(a0.x * sa, a0.y * sa, 0, false);
    v0 = __builtin_amdgcn_cvt_pk_fp8_f32(a0.z * sa, a0.w * sa, v0, true);
    int v1 = __builtin_amdgcn_cvt_pk_fp8_f32(a1.x * sa, a1.y * sa, 0, false);
    v1 = __builtin_amdgcn_cvt_pk_fp8_f32(a1.z * sa, a1.w * sa, v1, true);
    int2 pv; pv.x = v0; pv.y = v1;
    *(int2*)(An + (size_t)row * DK + doff) = pv;
  }
  {
    int v0 = __builtin_amdgcn_cvt_pk_fp8_f32(b0.x * sb, b0.y * sb, 0, false);
    v0 = __builtin_amdgcn_cvt_pk_fp8_f32(b0.z * sb, b0.w * sb, v0, true);
    int v1 = __builtin_amdgcn_cvt_pk_fp8_f32(b1.x * sb, b1.y * sb, 0, false);
    v1 = __builtin_amdgcn_cvt_pk_fp8_f32(b1.z * sb, b1.w * sb, v1, true);
    int2 pv; pv.x = v0; pv.y = v1;
    *(int2*)(Bn + (size_t)row * DK + doff) = pv;
  }
  if (lane == 0) diag[row] = (sab / (na * nb)) * 10.0f;  // exact fp32 /TAU
}

// ---------------- tiles: symmetric pair blocks, MX fp8, dual harvest ------
// grid = 528 pair blocks (~2/CU). 4 waves/block, wave owns 32 rows of panel
// bi (both views resident). Loop u=0..7: v=u>>2 (col view), t=u&3 (32-col
// tile of panel bj). 16 KB tiles, dbuf LDS.
__global__ void __launch_bounds__(256, 2) tiles_kernel(
    const unsigned char* __restrict__ An, const unsigned char* __restrict__ Bn,
    float* __restrict__ accLA, float* __restrict__ accLB,
    unsigned* __restrict__ accMA) {
  __shared__ __align__(16) unsigned char smem[2 * TILE_BYTES];  // 32 KB
  __shared__ float colS[2][4][4][32];  // [v][t][wave][col] exp-sums
  __shared__ float colM[4][4][32];     // [t][wave][col] max (v=0 only)

  // decode pair (bi <= bj)
  int p = blockIdx.x;
  int bi = 0;
  while (p >= NB - bi) { p -= NB - bi; ++bi; }
  const int bj = bi + p;
  const bool diagb = (bi == bj);

  const int tid = threadIdx.x;
  const int lane = tid & 63, w = tid >> 6;
  const int n5 = lane & 31, h = lane >> 5;
  const int r0 = bi * 128;
  const int myrow = r0 + w * 32 + n5;
  const int c0 = bj * 128;  // column panel base

  // both views' left K=64 MX operands: aw[i] = chunks (2i,h)||(2i+1,h)
  intx8 awA[8], awB[8];
  {
    const unsigned char* pA = An + (size_t)myrow * DK + h * 16;
    const unsigned char* pB = Bn + (size_t)myrow * DK + h * 16;
#pragma unroll
    for (int i = 0; i < 8; ++i) {
      int4 q0 = *(const int4*)(pA + i * 64);
      int4 q1 = *(const int4*)(pA + i * 64 + 32);
      intx8 va = {q0.x, q0.y, q0.z, q0.w, q1.x, q1.y, q1.z, q1.w};
      awA[i] = va;
      q0 = *(const int4*)(pB + i * 64);
      q1 = *(const int4*)(pB + i * 64 + 32);
      intx8 vb = {q0.x, q0.y, q0.z, q0.w, q1.x, q1.y, q1.z, q1.w};
      awB[i] = vb;
    }
  }

  // row-dir state (rows of panel bi): lA -> full_a, lB -> full_b; mx = full_a
  float lA[16], lB[16], mx[16];
#pragma unroll
  for (int r = 0; r < 16; ++r) { lA[r] = 0.f; lB[r] = 0.f; mx[r] = NEG_BIG; }

  // stage tile u (v=u>>2, t=u&3): 32 cols of view v, panel bj. One inst =
  // 2 cols. XOR swizzle: physical chunk pp of col c holds logical pp^(c&7).
  auto stage = [&](unsigned char* buf, int u) {
    const unsigned char* csrc = (u < 4) ? An : Bn;
    const int cb = c0 + (u & 3) * 32;
#pragma unroll
    for (int ii = 0; ii < 4; ++ii) {  // wave w: colpairs w*4 .. w*4+3
      const int cp = w * 4 + ii;
      const int cl = cp * 2 + h;
      const unsigned char* src =
          csrc + (size_t)(cb + cl) * DK + ((n5 ^ (cl & 7)) * 16);
      __builtin_amdgcn_global_load_lds(
          (const __attribute__((address_space(1))) void*)src,
          (__attribute__((address_space(3))) void*)(buf + cp * 1024),
          16, 0, 0);
    }
  };

  stage(smem, 0);
  __syncthreads();

  const int swz = n5 & 7;
  for (int u = 0; u < 8; ++u) {
    const int v = u >> 2, t = u & 3;
    unsigned char* cur = smem + (u & 1) * TILE_BYTES;
    unsigned char* nxt = smem + ((u + 1) & 1) * TILE_BYTES;
    if (u < 7) stage(nxt, u + 1);  // prefetch; drained at this iter's barrier

    floatx16 accA, accB;
#pragma unroll
    for (int r = 0; r < 16; ++r) { accA[r] = 0.f; accB[r] = 0.f; }

    // B K=64 operand: logical chunks (4i+h),(4i+2+h) of col n5; one staged
    // operand feeds BOTH left views (a_i and b_i).
    const unsigned char* bbase = cur + (size_t)n5 * DK;
#pragma unroll
    for (int i = 0; i < 8; ++i) {
      const int p1 = ((4 * i + h) ^ swz) * 16;
      const int p2 = ((4 * i + 2 + h) ^ swz) * 16;
      int4 q0 = *(const int4*)(bbase + p1);
      int4 q1 = *(const int4*)(bbase + p2);
      intx8 bw = {q0.x, q0.y, q0.z, q0.w, q1.x, q1.y, q1.z, q1.w};
      accA = __builtin_amdgcn_mfma_scale_f32_32x32x64_f8f6f4(
          awA[i], bw, accA, 0, 0, 0, 0x7F7F7F7F, 0, 0x7F7F7F7F);
      accB = __builtin_amdgcn_mfma_scale_f32_32x32x64_f8f6f4(
          awB[i], bw, accB, 0, 0, 0, 0x7F7F7F7F, 0, 0x7F7F7F7F);
    }

    // harvest: row-dir always; col-dir partials to LDS (off-diagonal only).
    const int colbase = c0 + t * 32;
    float cS = 0.f, cM = NEG_BIG;  // this lane's col = colbase + n5
#pragma unroll
    for (int r = 0; r < 16; ++r) {
      float vA = accA[r], vB = accB[r];
      if (diagb) {  // mask (i,i): aa/bb diag and ab/ba label (re-added later)
        const int rowg = r0 + w * 32 + (r & 3) + 8 * (r >> 2) + 4 * h;
        if (rowg == colbase + n5) { vA = NEG_BIG; vB = NEG_BIG; }
      }
      mx[r] = fmaxf(mx[r], vA);  // accA is always a full_a contribution
      float eA = exp2f(fmaf(vA, SCL2, -C2));
      float eB = exp2f(fmaf(vB, SCL2, -C2));
      lA[r] += eA;
      lB[r] += eB;
      cS += eA + eB;  // both accs' col c target the same problem (header)
      if (v == 0) cM = fmaxf(cM, fmaxf(vA, vB));  // full_a col max
    }
    if (!diagb) {
      cS += __shfl_xor(cS, 32);  // merge the two half-wave row-groups
      if (v == 0) cM = fmaxf(cM, __shfl_xor(cM, 32));
      if (h == 0) {
        colS[v][t][w][n5] = cS;
        if (v == 0) colM[t][w][n5] = cM;
      }
    }
    __syncthreads();  // cur consumed; nxt's DMA drained; colS visible later
  }

  // ---- single flush: row-dir (registers) + col-dir (LDS), one drain ----
#pragma unroll
  for (int off = 1; off < 32; off <<= 1)
#pragma unroll
    for (int r = 0; r < 16; ++r) {
      lA[r] += __shfl_xor(lA[r], off);
      lB[r] += __shfl_xor(lB[r], off);
      mx[r] = fmaxf(mx[r], __shfl_xor(mx[r], off));
    }
  if (n5 == 0) {
#pragma unroll
    for (int r = 0; r < 16; ++r) {
      const int row = r0 + w * 32 + (r & 3) + 8 * (r >> 2) + 4 * h;
      atomicAdd(&accLA[row], lA[r]);
      atomicAdd(&accLB[row], lB[r]);
      atomicMax(&accMA[row], __float_as_uint(mx[r] * SCL + 20.0f));
    }
  }
  if (!diagb) {  // col-dir flush: 256 threads cover [v][t][col]
    const int vv = tid >> 7, tt = (tid >> 5) & 3, cc = tid & 31;
    float s = colS[vv][tt][0][cc] + colS[vv][tt][1][cc] +
              colS[vv][tt][2][cc] + colS[vv][tt][3][cc];
    float* dst = vv ? accLB : accLA;
    atomicAdd(&dst[c0 + tt * 32 + cc], s);
    if (tid < 128) {
      float m = fmaxf(fmaxf(colM[tt][0][cc], colM[tt][1][cc]),
                      fmaxf(colM[tt][2][cc], colM[tt][3][cc]));
      atomicMax(&accMA[c0 + tt * 32 + cc], __float_as_uint(m * SCL + 20.0f));
    }
  }
}

// ---------------- finalize: add label, loss + accuracy reduce -------------
// NOTE: no zeroing here — zero_out_kernel owns it (r12 race lesson).
__global__ void __launch_bounds__(256) finalize_kernel(
    const float* __restrict__ accLA, const float* __restrict__ accLB,
    const unsigned* __restrict__ accMA, const float* __restrict__ diag,
    float* __restrict__ out) {
  const int row = blockIdx.x * 256 + threadIdx.x;
  const float SA = accLA[row], SB = accLB[row];
  const float MA = __uint_as_float(accMA[row]) - 20.0f;  // max non-label logit
  const float d = diag[row];
  const float eL = exp2f(fmaf(d, 1.44269504f, -C2));     // exp(d-10)
  float lossi = (10.0f + logf(SA + eL) - d) + (10.0f + logf(SB + eL) - d);
  float corr = (d >= MA) ? 1.f : 0.f;  // argmax(full_a)==label
#pragma unroll
  for (int off = 32; off > 0; off >>= 1) {
    lossi += __shfl_xor(lossi, off);
    corr += __shfl_xor(corr, off);
  }
  __shared__ float sred[2][4];
  if ((threadIdx.x & 63) == 0) {
    int w = threadIdx.x >> 6;
    sred[0][w] = lossi; sred[1][w] = corr;
  }
  __syncthreads();
  if (threadIdx.x == 0) {
    float ls = sred[0][0] + sred[0][1] + sred[0][2] + sred[0][3];
    float cs = sred[1][0] + sred[1][1] + sred[1][2] + sred[1][3];
    atomicAdd(&out[0], ls * (1.0f / 8192.0f));    // mean over rows, /2
    atomicAdd(&out[1], cs * (100.0f / 4096.0f));  // accuracy %
  }
}

// zero the two outputs before finalize accumulates (out poisoned by harness)
__global__ void zero_out_kernel(float* out) {
  if (threadIdx.x < 2) out[threadIdx.x] = 0.0f;
}

extern "C" void kernel_launch(void* const* d_in, const int* in_sizes, int n_in,
                              void* d_out, int out_size, void* d_ws, size_t ws_size,
                              hipStream_t stream) {
  const float* A = (const float*)d_in[0];
  const float* Bv = (const float*)d_in[1];
  unsigned char* An = (unsigned char*)d_ws;                   // 4096x512 fp8
  unsigned char* Bn = An + (size_t)BN * DK;                   // 4096x512 fp8
  float* diag = (float*)(Bn + (size_t)BN * DK);               // 4096 f32
  float* accLA = diag + BN;                                   // 4096 f32
  float* accLB = accLA + BN;                                  // 4096 f32
  unsigned* accMA = (unsigned*)(accLB + BN);                  // 4096 u32
  float* out = (float*)d_out;

  zero_out_kernel<<<1, 64, 0, stream>>>(out);
  prep_kernel<<<BN / 4, 256, 0, stream>>>(A, Bv, An, Bn, diag, accLA);
  tiles_kernel<<<NB * (NB + 1) / 2, 256, 0, stream>>>(An, Bn, accLA, accLB, accMA);
  finalize_kernel<<<BN / 256, 256, 0, stream>>>(accLA, accLB, accMA, diag, out);
}